// Round 1
// baseline (1644.692 us; speedup 1.0000x reference)
//
#include <hip/hip_runtime.h>
#include <cstdint>
#include <cstddef>

#define KNN 16
#define NPTS 256
#define NBATCH 128

static constexpr float BN_SCALE_F = 0.9999950000374997f; // 1/sqrt(1+1e-5)

__device__ inline unsigned int f32_ord(float f) {
    unsigned int u = __float_as_uint(f);
    // map float order -> unsigned order (handles negatives from fp rounding)
    return (u & 0x80000000u) ? ~u : (u | 0x80000000u);
}

// ---------------------------------------------------------------------------
// kNN: one block per (batch, point i); 256 threads, thread j owns distance
// d2(i,j) = sq_i + sq_j - 2*dot (same formula as reference). 16 rounds of
// argmin over a u64 (ordered-dist<<32 | j) so ties break to smaller index,
// matching lax.top_k. Self-distance masked to +inf.
// ---------------------------------------------------------------------------
template<int D>
__global__ __launch_bounds__(256) void knn_kernel(const float* __restrict__ x,
                                                  int* __restrict__ idx) {
    const int bi = blockIdx.x;      // b*256 + i
    const int i  = bi & 255;
    const int j  = threadIdx.x;
    __shared__ float xi[D];
    const float* xrow_i = x + (size_t)bi * D;
    for (int d = j; d < D; d += 256) xi[d] = xrow_i[d];
    __syncthreads();

    const int b0 = bi & ~255;       // b*256
    const float* xrow_j = x + (size_t)(b0 + j) * D;
    float sqi = 0.f, sqj = 0.f, dot = 0.f;
    for (int d = 0; d < D; ++d) {
        float a = xi[d];
        float c = xrow_j[d];
        sqi = fmaf(a, a, sqi);
        sqj = fmaf(c, c, sqj);
        dot = fmaf(a, c, dot);
    }
    float d2 = sqi + sqj - 2.f * dot;
    unsigned long long key =
        ((unsigned long long)f32_ord(d2) << 32) | (unsigned int)j;
    if (j == i) key = ~0ull;

    __shared__ unsigned long long wmin[4];
    __shared__ int winner;
    int* out = idx + (size_t)bi * KNN;
    for (int r = 0; r < KNN; ++r) {
        unsigned long long v = key;
        #pragma unroll
        for (int off = 32; off >= 1; off >>= 1) {
            unsigned long long o = __shfl_xor(v, off, 64);
            v = (o < v) ? o : v;
        }
        if ((j & 63) == 0) wmin[j >> 6] = v;
        __syncthreads();
        if (j == 0) {
            unsigned long long m0 = wmin[0] < wmin[1] ? wmin[0] : wmin[1];
            unsigned long long m1 = wmin[2] < wmin[3] ? wmin[2] : wmin[3];
            unsigned long long m  = m0 < m1 ? m0 : m1;
            int w = (int)(unsigned int)(m & 0xffffffffull);
            out[r] = w;
            winner = w;
        }
        __syncthreads();
        if (j == winner) key = ~0ull;
    }
}

// ---------------------------------------------------------------------------
// Factorized edge-MLP, point-level part.
//   h(i,j) = concat(x_i, x_j - x_i) @ W + b = x_i@(Wt-Wb) + x_j@Wb + b
//   bn(h)  = g*BN*h + be = A_i + Bv_j, with
//   A_i  = (g*BN) * (x_i @ (Wt-Wb))
//   Bv_j = (g*BN) * (x_j @ Wb + b) + be
// One block per point, one thread per output channel.
// ---------------------------------------------------------------------------
template<int D, int C>
__global__ __launch_bounds__(C) void point_mlp_kernel(
        const float* __restrict__ x, const float* __restrict__ W,
        const float* __restrict__ bias, const float* __restrict__ g,
        const float* __restrict__ be,
        float* __restrict__ A, float* __restrict__ Bv) {
    const int bi = blockIdx.x;
    const int c  = threadIdx.x;
    __shared__ float xi[D];
    const float* xrow = x + (size_t)bi * D;
    for (int d = c; d < D; d += C) xi[d] = xrow[d];
    __syncthreads();

    float accU = 0.f, accV = 0.f;
    for (int d = 0; d < D; ++d) {
        float xv = xi[d];
        float wt = W[(size_t)d * C + c];        // top half row d
        float wb = W[(size_t)(D + d) * C + c];  // bottom half row d
        accU = fmaf(xv, wt - wb, accU);
        accV = fmaf(xv, wb, accV);
    }
    float gc = g[c] * BN_SCALE_F;
    A [(size_t)bi * C + c] = gc * accU;
    Bv[(size_t)bi * C + c] = gc * (accV + bias[c]) + be[c];
}

// ---------------------------------------------------------------------------
// Combine: out[i][c] = relu(A[i][c] + max_{j in knn(i)} Bv[j][c]).
// out may alias A (row i only read/written by block i) -> no restrict on A/out.
// ---------------------------------------------------------------------------
template<int C>
__global__ __launch_bounds__(C) void combine_kernel(
        const float* A, const float* __restrict__ Bv,
        const int* __restrict__ idx, float* out) {
    const int bi = blockIdx.x;
    const int c  = threadIdx.x;
    __shared__ int nbr[KNN];
    if (c < KNN) nbr[c] = idx[(size_t)bi * KNN + c];
    __syncthreads();
    const int b0 = bi & ~255;
    float mx = -INFINITY;
    #pragma unroll
    for (int kk = 0; kk < KNN; ++kk) {
        mx = fmaxf(mx, Bv[(size_t)(b0 + nbr[kk]) * C + c]);
    }
    float a = A[(size_t)bi * C + c];
    out[(size_t)bi * C + c] = fmaxf(a + mx, 0.f);
}

// ---------------------------------------------------------------------------
// Head: global max-pool over N, then 2 tiny FCs. One block per batch.
// ---------------------------------------------------------------------------
__global__ __launch_bounds__(256) void head_kernel(
        const float* __restrict__ h3, const float* __restrict__ Wf1,
        const float* __restrict__ bf1, const float* __restrict__ gf,
        const float* __restrict__ bef, const float* __restrict__ Wf2,
        const float* __restrict__ bf2, float* __restrict__ out) {
    const int b   = blockIdx.x;
    const int tid = threadIdx.x;
    __shared__ float p[256];
    __shared__ float f[128];
    const float* hb = h3 + (size_t)b * NPTS * 256;
    float mx = -INFINITY;
    for (int n = 0; n < NPTS; ++n) mx = fmaxf(mx, hb[(size_t)n * 256 + tid]);
    p[tid] = mx;
    __syncthreads();
    if (tid < 128) {
        float acc = bf1[tid];
        for (int d = 0; d < 256; ++d)
            acc = fmaf(p[d], Wf1[(size_t)d * 128 + tid], acc);
        float v = gf[tid] * (acc * BN_SCALE_F) + bef[tid];
        f[tid] = fmaxf(v, 0.f);
    }
    __syncthreads();
    if (tid < 12) {
        float acc = bf2[tid];
        for (int d = 0; d < 128; ++d)
            acc = fmaf(f[d], Wf2[(size_t)d * 12 + tid], acc);
        out[(size_t)b * 12 + tid] = acc;
    }
}

extern "C" void kernel_launch(void* const* d_in, const int* in_sizes, int n_in,
                              void* d_out, int out_size, void* d_ws, size_t ws_size,
                              hipStream_t stream) {
    const float* x   = (const float*)d_in[0];
    const float* W1  = (const float*)d_in[1];
    const float* b1  = (const float*)d_in[2];
    const float* g1  = (const float*)d_in[3];
    const float* be1 = (const float*)d_in[4];
    const float* W2  = (const float*)d_in[5];
    const float* b2  = (const float*)d_in[6];
    const float* g2  = (const float*)d_in[7];
    const float* be2 = (const float*)d_in[8];
    const float* W3  = (const float*)d_in[9];
    const float* b3  = (const float*)d_in[10];
    const float* g3  = (const float*)d_in[11];
    const float* be3 = (const float*)d_in[12];
    const float* Wf1 = (const float*)d_in[13];
    const float* bf1 = (const float*)d_in[14];
    const float* gf  = (const float*)d_in[15];
    const float* bef = (const float*)d_in[16];
    const float* Wf2 = (const float*)d_in[17];
    const float* bf2 = (const float*)d_in[18];
    float* out = (float*)d_out;

    char* ws = (char*)d_ws;
    const size_t idx_bytes = (size_t)NBATCH * NPTS * KNN * sizeof(int);   // 2 MB
    const size_t reg_bytes = (size_t)NBATCH * NPTS * 256 * sizeof(float); // 32 MB
    int*   idx = (int*)ws;
    float* R1  = (float*)(ws + idx_bytes);
    float* R2  = (float*)(ws + idx_bytes + reg_bytes);
    float* R3  = (float*)(ws + idx_bytes + 2 * reg_bytes);

    const int BN = NBATCH * NPTS; // 32768 blocks

    // ---- Layer 1: x (D=6) -> h1 (C=64) in R1 ----
    knn_kernel<6><<<BN, 256, 0, stream>>>(x, idx);
    point_mlp_kernel<6, 64><<<BN, 64, 0, stream>>>(x, W1, b1, g1, be1, R1, R2);
    combine_kernel<64><<<BN, 64, 0, stream>>>(R1, R2, idx, R1);   // h1 = R1

    // ---- Layer 2: h1 (D=64) -> h2 (C=128) in R2 ----
    knn_kernel<64><<<BN, 256, 0, stream>>>(R1, idx);
    point_mlp_kernel<64, 128><<<BN, 128, 0, stream>>>(R1, W2, b2, g2, be2, R2, R3);
    combine_kernel<128><<<BN, 128, 0, stream>>>(R2, R3, idx, R2); // h2 = R2

    // ---- Layer 3: h2 (D=128) -> h3 (C=256) in R3 ----
    knn_kernel<128><<<BN, 256, 0, stream>>>(R2, idx);
    point_mlp_kernel<128, 256><<<BN, 256, 0, stream>>>(R2, W3, b3, g3, be3, R3, R1);
    combine_kernel<256><<<BN, 256, 0, stream>>>(R3, R1, idx, R3); // h3 = R3

    // ---- Head ----
    head_kernel<<<NBATCH, 256, 0, stream>>>(R3, Wf1, bf1, gf, bef, Wf2, bf2, out);
}

// Round 2
// 1399.913 us; speedup vs baseline: 1.1749x; 1.1749x over previous
//
#include <hip/hip_runtime.h>
#include <cstdint>
#include <cstddef>

#define KNN 16
#define NPTS 256
#define NBATCH 128

static constexpr float BN_SCALE_F = 0.9999950000374997f; // 1/sqrt(1+1e-5)

// ---------------------------------------------------------------------------
// sq[t] = sum_d x[t][d]^2, fmaf chain in d order (matches knn's sqi chain).
// One thread per point.
// ---------------------------------------------------------------------------
template<int D>
__global__ __launch_bounds__(256) void sq_kernel(const float* __restrict__ x,
                                                 float* __restrict__ sq) {
    const int t = blockIdx.x * 256 + threadIdx.x;
    const float* r = x + (size_t)t * D;
    float s = 0.f;
    #pragma unroll
    for (int d = 0; d < D; ++d) s = fmaf(r[d], r[d], s);
    sq[t] = s;
}

// ---------------------------------------------------------------------------
// kNN v2: ONE WAVE PER POINT, no barriers, no LDS.
// Lane l owns candidates j = l + 64*s (s=0..3). d2 = sq_i + sq_j - 2*dot,
// dot accumulated as a sequential fmaf chain over d (bit-identical to r1,
// which matched the reference's top_k ordering exactly).
// Selection: 16 rounds of wave fminf-butterfly + ballot; winner = smallest
// distance, ties broken by smallest index j (slot-major scan = index order),
// matching lax.top_k stability. Killed/self candidates = +inf.
// ---------------------------------------------------------------------------
template<int D>
__global__ __launch_bounds__(256) void knn2_kernel(const float* __restrict__ x,
                                                   const float* __restrict__ sq,
                                                   int* __restrict__ idx) {
    const int lane = threadIdx.x & 63;
    const int wv   = __builtin_amdgcn_readfirstlane((int)(threadIdx.x >> 6));
    const int ig   = blockIdx.x * 4 + wv;     // global point id = b*256 + i
    const int i    = ig & 255;
    const int b0   = ig & ~255;

    const float* __restrict__ xi = x + (size_t)ig * D;            // wave-uniform
    const float* __restrict__ p0 = x + (size_t)(b0 + lane      ) * D;
    const float* __restrict__ p1 = x + (size_t)(b0 + lane +  64) * D;
    const float* __restrict__ p2 = x + (size_t)(b0 + lane + 128) * D;
    const float* __restrict__ p3 = x + (size_t)(b0 + lane + 192) * D;

    float a0 = 0.f, a1 = 0.f, a2 = 0.f, a3 = 0.f;
    if constexpr (D % 4 == 0) {
        for (int d = 0; d < D; d += 4) {
            const float4 v  = *(const float4*)(xi + d);
            const float4 q0 = *(const float4*)(p0 + d);
            const float4 q1 = *(const float4*)(p1 + d);
            const float4 q2 = *(const float4*)(p2 + d);
            const float4 q3 = *(const float4*)(p3 + d);
            a0 = fmaf(v.x, q0.x, a0); a0 = fmaf(v.y, q0.y, a0);
            a0 = fmaf(v.z, q0.z, a0); a0 = fmaf(v.w, q0.w, a0);
            a1 = fmaf(v.x, q1.x, a1); a1 = fmaf(v.y, q1.y, a1);
            a1 = fmaf(v.z, q1.z, a1); a1 = fmaf(v.w, q1.w, a1);
            a2 = fmaf(v.x, q2.x, a2); a2 = fmaf(v.y, q2.y, a2);
            a2 = fmaf(v.z, q2.z, a2); a2 = fmaf(v.w, q2.w, a2);
            a3 = fmaf(v.x, q3.x, a3); a3 = fmaf(v.y, q3.y, a3);
            a3 = fmaf(v.z, q3.z, a3); a3 = fmaf(v.w, q3.w, a3);
        }
    } else {
        for (int d = 0; d < D; d += 2) {
            const float2 v  = *(const float2*)(xi + d);
            const float2 q0 = *(const float2*)(p0 + d);
            const float2 q1 = *(const float2*)(p1 + d);
            const float2 q2 = *(const float2*)(p2 + d);
            const float2 q3 = *(const float2*)(p3 + d);
            a0 = fmaf(v.x, q0.x, a0); a0 = fmaf(v.y, q0.y, a0);
            a1 = fmaf(v.x, q1.x, a1); a1 = fmaf(v.y, q1.y, a1);
            a2 = fmaf(v.x, q2.x, a2); a2 = fmaf(v.y, q2.y, a2);
            a3 = fmaf(v.x, q3.x, a3); a3 = fmaf(v.y, q3.y, a3);
        }
    }

    const float sqi = sq[ig];
    float k0 = sqi + sq[b0 + lane      ] - 2.f * a0;
    float k1 = sqi + sq[b0 + lane +  64] - 2.f * a1;
    float k2 = sqi + sq[b0 + lane + 128] - 2.f * a2;
    float k3 = sqi + sq[b0 + lane + 192] - 2.f * a3;

    // mask self
    const int li = i & 63, si = i >> 6;
    if (lane == li) {
        if (si == 0) k0 = INFINITY;
        else if (si == 1) k1 = INFINITY;
        else if (si == 2) k2 = INFINITY;
        else k3 = INFINITY;
    }

    int myj = 0;
    #pragma unroll
    for (int r = 0; r < KNN; ++r) {
        float m = fminf(fminf(k0, k1), fminf(k2, k3));
        #pragma unroll
        for (int off = 32; off >= 1; off >>= 1)
            m = fminf(m, __shfl_xor(m, off, 64));
        // recover winner: smallest index j with distance == m
        unsigned long long B0 = __ballot(k0 == m);
        unsigned long long B1 = __ballot(k1 == m);
        unsigned long long B2 = __ballot(k2 == m);
        unsigned long long B3 = __ballot(k3 == m);
        int j;
        if (B0)      j =       __builtin_ctzll(B0);
        else if (B1) j =  64 + __builtin_ctzll(B1);
        else if (B2) j = 128 + __builtin_ctzll(B2);
        else         j = 192 + __builtin_ctzll(B3);
        if (lane == r) myj = j;
        // kill winner
        if (lane == (j & 63)) {
            const int s = j >> 6;
            k0 = (s == 0) ? INFINITY : k0;
            k1 = (s == 1) ? INFINITY : k1;
            k2 = (s == 2) ? INFINITY : k2;
            k3 = (s == 3) ? INFINITY : k3;
        }
    }
    if (lane < KNN) idx[(size_t)ig * KNN + lane] = myj;
}

// ---------------------------------------------------------------------------
// Factorized edge-MLP, point-level part (unchanged from r1, known-correct).
//   A_i  = (g*BN) * (x_i @ (Wt-Wb))
//   Bv_j = (g*BN) * (x_j @ Wb + b) + be
// ---------------------------------------------------------------------------
template<int D, int C>
__global__ __launch_bounds__(C) void point_mlp_kernel(
        const float* __restrict__ x, const float* __restrict__ W,
        const float* __restrict__ bias, const float* __restrict__ g,
        const float* __restrict__ be,
        float* __restrict__ A, float* __restrict__ Bv) {
    const int bi = blockIdx.x;
    const int c  = threadIdx.x;
    __shared__ float xi[D];
    const float* xrow = x + (size_t)bi * D;
    for (int d = c; d < D; d += C) xi[d] = xrow[d];
    __syncthreads();

    float accU = 0.f, accV = 0.f;
    for (int d = 0; d < D; ++d) {
        float xv = xi[d];
        float wt = W[(size_t)d * C + c];
        float wb = W[(size_t)(D + d) * C + c];
        accU = fmaf(xv, wt - wb, accU);
        accV = fmaf(xv, wb, accV);
    }
    float gc = g[c] * BN_SCALE_F;
    A [(size_t)bi * C + c] = gc * accU;
    Bv[(size_t)bi * C + c] = gc * (accV + bias[c]) + be[c];
}

// ---------------------------------------------------------------------------
// Combine: out[i][c] = relu(A[i][c] + max_{j in knn(i)} Bv[j][c]). out aliases A.
// ---------------------------------------------------------------------------
template<int C>
__global__ __launch_bounds__(C) void combine_kernel(
        const float* A, const float* __restrict__ Bv,
        const int* __restrict__ idx, float* out) {
    const int bi = blockIdx.x;
    const int c  = threadIdx.x;
    __shared__ int nbr[KNN];
    if (c < KNN) nbr[c] = idx[(size_t)bi * KNN + c];
    __syncthreads();
    const int b0 = bi & ~255;
    float mx = -INFINITY;
    #pragma unroll
    for (int kk = 0; kk < KNN; ++kk)
        mx = fmaxf(mx, Bv[(size_t)(b0 + nbr[kk]) * C + c]);
    float a = A[(size_t)bi * C + c];
    out[(size_t)bi * C + c] = fmaxf(a + mx, 0.f);
}

// ---------------------------------------------------------------------------
// Head: global max-pool over N, then 2 tiny FCs. One block per batch.
// ---------------------------------------------------------------------------
__global__ __launch_bounds__(256) void head_kernel(
        const float* __restrict__ h3, const float* __restrict__ Wf1,
        const float* __restrict__ bf1, const float* __restrict__ gf,
        const float* __restrict__ bef, const float* __restrict__ Wf2,
        const float* __restrict__ bf2, float* __restrict__ out) {
    const int b   = blockIdx.x;
    const int tid = threadIdx.x;
    __shared__ float p[256];
    __shared__ float f[128];
    const float* hb = h3 + (size_t)b * NPTS * 256;
    float mx = -INFINITY;
    for (int n = 0; n < NPTS; ++n) mx = fmaxf(mx, hb[(size_t)n * 256 + tid]);
    p[tid] = mx;
    __syncthreads();
    if (tid < 128) {
        float acc = bf1[tid];
        for (int d = 0; d < 256; ++d)
            acc = fmaf(p[d], Wf1[(size_t)d * 128 + tid], acc);
        float v = gf[tid] * (acc * BN_SCALE_F) + bef[tid];
        f[tid] = fmaxf(v, 0.f);
    }
    __syncthreads();
    if (tid < 12) {
        float acc = bf2[tid];
        for (int d = 0; d < 128; ++d)
            acc = fmaf(f[d], Wf2[(size_t)d * 12 + tid], acc);
        out[(size_t)b * 12 + tid] = acc;
    }
}

extern "C" void kernel_launch(void* const* d_in, const int* in_sizes, int n_in,
                              void* d_out, int out_size, void* d_ws, size_t ws_size,
                              hipStream_t stream) {
    const float* x   = (const float*)d_in[0];
    const float* W1  = (const float*)d_in[1];
    const float* b1  = (const float*)d_in[2];
    const float* g1  = (const float*)d_in[3];
    const float* be1 = (const float*)d_in[4];
    const float* W2  = (const float*)d_in[5];
    const float* b2  = (const float*)d_in[6];
    const float* g2  = (const float*)d_in[7];
    const float* be2 = (const float*)d_in[8];
    const float* W3  = (const float*)d_in[9];
    const float* b3  = (const float*)d_in[10];
    const float* g3  = (const float*)d_in[11];
    const float* be3 = (const float*)d_in[12];
    const float* Wf1 = (const float*)d_in[13];
    const float* bf1 = (const float*)d_in[14];
    const float* gf  = (const float*)d_in[15];
    const float* bef = (const float*)d_in[16];
    const float* Wf2 = (const float*)d_in[17];
    const float* bf2 = (const float*)d_in[18];
    float* out = (float*)d_out;

    char* ws = (char*)d_ws;
    const size_t idx_bytes = (size_t)NBATCH * NPTS * KNN * sizeof(int);   // 2 MB
    const size_t reg_bytes = (size_t)NBATCH * NPTS * 256 * sizeof(float); // 32 MB
    int*   idx = (int*)ws;
    float* R1  = (float*)(ws + idx_bytes);
    float* R2  = (float*)(ws + idx_bytes + reg_bytes);
    float* R3  = (float*)(ws + idx_bytes + 2 * reg_bytes);
    float* sqb = (float*)(ws + idx_bytes + 3 * reg_bytes);                // 128 KB

    const int BN = NBATCH * NPTS; // 32768 points

    // ---- Layer 1: x (D=6) -> h1 (C=64) in R1 ----
    sq_kernel<6><<<BN / 256, 256, 0, stream>>>(x, sqb);
    knn2_kernel<6><<<BN / 4, 256, 0, stream>>>(x, sqb, idx);
    point_mlp_kernel<6, 64><<<BN, 64, 0, stream>>>(x, W1, b1, g1, be1, R1, R2);
    combine_kernel<64><<<BN, 64, 0, stream>>>(R1, R2, idx, R1);   // h1 = R1

    // ---- Layer 2: h1 (D=64) -> h2 (C=128) in R2 ----
    sq_kernel<64><<<BN / 256, 256, 0, stream>>>(R1, sqb);
    knn2_kernel<64><<<BN / 4, 256, 0, stream>>>(R1, sqb, idx);
    point_mlp_kernel<64, 128><<<BN, 128, 0, stream>>>(R1, W2, b2, g2, be2, R2, R3);
    combine_kernel<128><<<BN, 128, 0, stream>>>(R2, R3, idx, R2); // h2 = R2

    // ---- Layer 3: h2 (D=128) -> h3 (C=256) in R3 ----
    sq_kernel<128><<<BN / 256, 256, 0, stream>>>(R2, sqb);
    knn2_kernel<128><<<BN / 4, 256, 0, stream>>>(R2, sqb, idx);
    point_mlp_kernel<128, 256><<<BN, 256, 0, stream>>>(R2, W3, b3, g3, be3, R3, R1);
    combine_kernel<256><<<BN, 256, 0, stream>>>(R3, R1, idx, R3); // h3 = R3

    // ---- Head ----
    head_kernel<<<NBATCH, 256, 0, stream>>>(R3, Wf1, bf1, gf, bef, Wf2, bf2, out);
}

// Round 3
// 765.717 us; speedup vs baseline: 2.1479x; 1.8282x over previous
//
#include <hip/hip_runtime.h>
#include <cstdint>
#include <cstddef>

#define KNN 16
#define NPTS 256
#define NBATCH 128

static constexpr float BN_SCALE_F = 0.9999950000374997f; // 1/sqrt(1+1e-5)

__device__ inline unsigned int f32_ord(float f) {
    unsigned int u = __float_as_uint(f);
    return (u & 0x80000000u) ? ~u : (u | 0x80000000u);
}

// ---------------------------------------------------------------------------
// sq[t] = sum_d x[t][d]^2, sequential fmaf chain (matches reference assoc).
// ---------------------------------------------------------------------------
template<int D>
__global__ __launch_bounds__(256) void sq_kernel(const float* __restrict__ x,
                                                 float* __restrict__ sq) {
    const int t = blockIdx.x * 256 + threadIdx.x;
    const float* r = x + (size_t)t * D;
    float s = 0.f;
    #pragma unroll
    for (int d = 0; d < D; ++d) s = fmaf(r[d], r[d], s);
    sq[t] = s;
}

// ---------------------------------------------------------------------------
// Distance GEMM: d2[b][i][j] = (sq_i + sq_j) - 2*dot(x_i, x_j), diag = +INF.
// 64x64 tile per block, 4x4 per thread, K-tiled LDS staging in [k][row]
// (transposed) layout so fragments are contiguous -> ds_read_b128.
// dot accumulated in ascending d order (bit-identical to r1/r2's passing
// chain); d2 expression (sqi+sqj)-2*dot matches reference association.
// ---------------------------------------------------------------------------
template<int D>
__global__ __launch_bounds__(256) void gram_kernel(const float* __restrict__ x,
                                                   const float* __restrict__ sq,
                                                   float* __restrict__ d2) {
    constexpr int KS = (D >= 16) ? 16 : D;
    const int t  = threadIdx.x;
    const int tx = t & 15, ty = t >> 4;
    const int b    = blockIdx.x >> 4;
    const int tile = blockIdx.x & 15;
    const int i0 = (tile & 3) * 64;
    const int j0 = (tile >> 2) * 64;
    const int base = b * NPTS;

    __shared__ float As[KS][68];
    __shared__ float Bs[KS][68];

    float acc[4][4] = {};
    for (int k0 = 0; k0 < D; k0 += KS) {
        if constexpr (D % 16 == 0) {
            const int r  = t >> 2;
            const int cq = (t & 3) * 4;
            const float4 va = *(const float4*)(x + (size_t)(base + i0 + r) * D + k0 + cq);
            const float4 vb = *(const float4*)(x + (size_t)(base + j0 + r) * D + k0 + cq);
            As[cq + 0][r] = va.x; As[cq + 1][r] = va.y;
            As[cq + 2][r] = va.z; As[cq + 3][r] = va.w;
            Bs[cq + 0][r] = vb.x; Bs[cq + 1][r] = vb.y;
            Bs[cq + 2][r] = vb.z; Bs[cq + 3][r] = vb.w;
        } else {
            for (int e = t; e < 64 * KS; e += 256) {
                const int r = e / KS, c = e % KS;
                As[c][r] = x[(size_t)(base + i0 + r) * D + k0 + c];
                Bs[c][r] = x[(size_t)(base + j0 + r) * D + k0 + c];
            }
        }
        __syncthreads();
        #pragma unroll
        for (int kk = 0; kk < KS; ++kk) {
            const float4 av = *(const float4*)&As[kk][ty * 4];
            const float4 bv = *(const float4*)&Bs[kk][tx * 4];
            const float am[4] = {av.x, av.y, av.z, av.w};
            const float bm[4] = {bv.x, bv.y, bv.z, bv.w};
            #pragma unroll
            for (int m = 0; m < 4; ++m)
                #pragma unroll
                for (int n = 0; n < 4; ++n)
                    acc[m][n] = fmaf(am[m], bm[n], acc[m][n]);
        }
        __syncthreads();
    }

    float sqi[4], sqj[4];
    #pragma unroll
    for (int m = 0; m < 4; ++m) {
        sqi[m] = sq[base + i0 + ty * 4 + m];
        sqj[m] = sq[base + j0 + tx * 4 + m];
    }
    #pragma unroll
    for (int m = 0; m < 4; ++m) {
        const int gi = i0 + ty * 4 + m;
        float v[4];
        #pragma unroll
        for (int n = 0; n < 4; ++n) {
            v[n] = (sqi[m] + sqj[n]) - 2.f * acc[m][n];
            if (gi == j0 + tx * 4 + n) v[n] = INFINITY;
        }
        float4* dst = (float4*)(d2 + ((size_t)b << 16) + (size_t)gi * NPTS + j0 + tx * 4);
        *dst = make_float4(v[0], v[1], v[2], v[3]);
    }
}

// ---------------------------------------------------------------------------
// Top-16 selection, pure VALU (no shuffles/ballots/branchy scalar ladders).
// 8 threads per point; thread scans 32 candidates, maintaining a 16-deep
// ascending insertion list of packed keys (f32_ord(d2)<<32 | j) -> exact
// lax.top_k ordering incl. smallest-index tie-break. Then an 8-way merge
// from LDS using static equality-advance (keys are unique).
// ---------------------------------------------------------------------------
__global__ __launch_bounds__(256) void topk_kernel(const float* __restrict__ d2,
                                                   int* __restrict__ idx) {
    const int t = threadIdx.x;
    const int p = t >> 3;          // local point 0..31
    const int q = t & 7;           // octant
    const int ig = blockIdx.x * 32 + p;
    const float* row = d2 + (size_t)ig * NPTS;

    unsigned long long L[16];
    #pragma unroll
    for (int r = 0; r < 16; ++r) L[r] = ~0ull;

    const int jb = q * 32;
    #pragma unroll
    for (int jj = 0; jj < 32; jj += 4) {
        const float4 v4 = *(const float4*)(row + jb + jj);
        const float vv[4] = {v4.x, v4.y, v4.z, v4.w};
        #pragma unroll
        for (int e = 0; e < 4; ++e) {
            const unsigned long long key =
                ((unsigned long long)f32_ord(vv[e]) << 32) |
                (unsigned int)(jb + jj + e);
            #pragma unroll
            for (int r = 15; r >= 1; --r)
                L[r] = (key < L[r]) ? ((key < L[r - 1]) ? L[r - 1] : key) : L[r];
            L[0] = (key < L[0]) ? key : L[0];
        }
    }

    __shared__ unsigned long long K[256][17]; // +1 pad: breaks bank aliasing
    #pragma unroll
    for (int r = 0; r < 16; ++r) K[t][r] = L[r];
    __syncthreads();

    if (t < 32) {
        const int pp  = t;
        const int igo = blockIdx.x * 32 + pp;
        int h[8];
        unsigned long long v[8];
        #pragma unroll
        for (int c = 0; c < 8; ++c) { h[c] = 0; v[c] = K[pp * 8 + c][0]; }
        int outj[16];
        #pragma unroll
        for (int r = 0; r < 16; ++r) {
            unsigned long long best = v[0];
            #pragma unroll
            for (int c = 1; c < 8; ++c) best = (v[c] < best) ? v[c] : best;
            outj[r] = (int)(unsigned int)(best & 0xffffffffull);
            #pragma unroll
            for (int c = 0; c < 8; ++c) {
                const bool hit = (v[c] == best);
                const int hn = h[c] + (hit ? 1 : 0);
                const unsigned long long nv = K[pp * 8 + c][hn & 15];
                v[c] = hit ? ((hn < 16) ? nv : ~0ull) : v[c];
                h[c] = hn;
            }
        }
        int4* op = (int4*)(idx + (size_t)igo * KNN);
        op[0] = make_int4(outj[0],  outj[1],  outj[2],  outj[3]);
        op[1] = make_int4(outj[4],  outj[5],  outj[6],  outj[7]);
        op[2] = make_int4(outj[8],  outj[9],  outj[10], outj[11]);
        op[3] = make_int4(outj[12], outj[13], outj[14], outj[15]);
    }
}

// ---------------------------------------------------------------------------
// Factorized edge-MLP, point-level part (unchanged, known-correct).
//   A_i  = (g*BN) * (x_i @ (Wt-Wb))
//   Bv_j = (g*BN) * (x_j @ Wb + b) + be
// ---------------------------------------------------------------------------
template<int D, int C>
__global__ __launch_bounds__(C) void point_mlp_kernel(
        const float* __restrict__ x, const float* __restrict__ W,
        const float* __restrict__ bias, const float* __restrict__ g,
        const float* __restrict__ be,
        float* __restrict__ A, float* __restrict__ Bv) {
    const int bi = blockIdx.x;
    const int c  = threadIdx.x;
    __shared__ float xi[D];
    const float* xrow = x + (size_t)bi * D;
    for (int d = c; d < D; d += C) xi[d] = xrow[d];
    __syncthreads();

    float accU = 0.f, accV = 0.f;
    for (int d = 0; d < D; ++d) {
        float xv = xi[d];
        float wt = W[(size_t)d * C + c];
        float wb = W[(size_t)(D + d) * C + c];
        accU = fmaf(xv, wt - wb, accU);
        accV = fmaf(xv, wb, accV);
    }
    float gc = g[c] * BN_SCALE_F;
    A [(size_t)bi * C + c] = gc * accU;
    Bv[(size_t)bi * C + c] = gc * (accV + bias[c]) + be[c];
}

// ---------------------------------------------------------------------------
// Combine: out[i][c] = relu(A[i][c] + max_{j in knn(i)} Bv[j][c]). out aliases A.
// ---------------------------------------------------------------------------
template<int C>
__global__ __launch_bounds__(C) void combine_kernel(
        const float* A, const float* __restrict__ Bv,
        const int* __restrict__ idx, float* out) {
    const int bi = blockIdx.x;
    const int c  = threadIdx.x;
    __shared__ int nbr[KNN];
    if (c < KNN) nbr[c] = idx[(size_t)bi * KNN + c];
    __syncthreads();
    const int b0 = bi & ~255;
    float mx = -INFINITY;
    #pragma unroll
    for (int kk = 0; kk < KNN; ++kk)
        mx = fmaxf(mx, Bv[(size_t)(b0 + nbr[kk]) * C + c]);
    float a = A[(size_t)bi * C + c];
    out[(size_t)bi * C + c] = fmaxf(a + mx, 0.f);
}

// ---------------------------------------------------------------------------
// Head: global max-pool over N, then 2 tiny FCs. One block per batch.
// ---------------------------------------------------------------------------
__global__ __launch_bounds__(256) void head_kernel(
        const float* __restrict__ h3, const float* __restrict__ Wf1,
        const float* __restrict__ bf1, const float* __restrict__ gf,
        const float* __restrict__ bef, const float* __restrict__ Wf2,
        const float* __restrict__ bf2, float* __restrict__ out) {
    const int b   = blockIdx.x;
    const int tid = threadIdx.x;
    __shared__ float p[256];
    __shared__ float f[128];
    const float* hb = h3 + (size_t)b * NPTS * 256;
    float mx = -INFINITY;
    for (int n = 0; n < NPTS; ++n) mx = fmaxf(mx, hb[(size_t)n * 256 + tid]);
    p[tid] = mx;
    __syncthreads();
    if (tid < 128) {
        float acc = bf1[tid];
        for (int d = 0; d < 256; ++d)
            acc = fmaf(p[d], Wf1[(size_t)d * 128 + tid], acc);
        float v = gf[tid] * (acc * BN_SCALE_F) + bef[tid];
        f[tid] = fmaxf(v, 0.f);
    }
    __syncthreads();
    if (tid < 12) {
        float acc = bf2[tid];
        for (int d = 0; d < 128; ++d)
            acc = fmaf(f[d], Wf2[(size_t)d * 12 + tid], acc);
        out[(size_t)b * 12 + tid] = acc;
    }
}

extern "C" void kernel_launch(void* const* d_in, const int* in_sizes, int n_in,
                              void* d_out, int out_size, void* d_ws, size_t ws_size,
                              hipStream_t stream) {
    const float* x   = (const float*)d_in[0];
    const float* W1  = (const float*)d_in[1];
    const float* b1  = (const float*)d_in[2];
    const float* g1  = (const float*)d_in[3];
    const float* be1 = (const float*)d_in[4];
    const float* W2  = (const float*)d_in[5];
    const float* b2  = (const float*)d_in[6];
    const float* g2  = (const float*)d_in[7];
    const float* be2 = (const float*)d_in[8];
    const float* W3  = (const float*)d_in[9];
    const float* b3  = (const float*)d_in[10];
    const float* g3  = (const float*)d_in[11];
    const float* be3 = (const float*)d_in[12];
    const float* Wf1 = (const float*)d_in[13];
    const float* bf1 = (const float*)d_in[14];
    const float* gf  = (const float*)d_in[15];
    const float* bef = (const float*)d_in[16];
    const float* Wf2 = (const float*)d_in[17];
    const float* bf2 = (const float*)d_in[18];
    float* out = (float*)d_out;

    char* ws = (char*)d_ws;
    const size_t idx_bytes = (size_t)NBATCH * NPTS * KNN * sizeof(int);   // 2 MB
    const size_t reg_bytes = (size_t)NBATCH * NPTS * 256 * sizeof(float); // 32 MB
    int*   idx = (int*)ws;
    float* R1  = (float*)(ws + idx_bytes);
    float* R2  = (float*)(ws + idx_bytes + reg_bytes);
    float* R3  = (float*)(ws + idx_bytes + 2 * reg_bytes);
    float* sqb = (float*)(ws + idx_bytes + 3 * reg_bytes);                // 128 KB

    const int BN = NBATCH * NPTS;        // 32768 points
    const int GRAM_GRID = NBATCH * 16;   // 2048 blocks
    const int TOPK_GRID = BN / 32;       // 1024 blocks

    // ---- Layer 1: x (D=6) -> h1 (C=64) in R1; d2 scratch = R3 ----
    sq_kernel<6><<<BN / 256, 256, 0, stream>>>(x, sqb);
    gram_kernel<6><<<GRAM_GRID, 256, 0, stream>>>(x, sqb, R3);
    topk_kernel<<<TOPK_GRID, 256, 0, stream>>>(R3, idx);
    point_mlp_kernel<6, 64><<<BN, 64, 0, stream>>>(x, W1, b1, g1, be1, R1, R2);
    combine_kernel<64><<<BN, 64, 0, stream>>>(R1, R2, idx, R1);   // h1 = R1

    // ---- Layer 2: h1 (D=64) -> h2 (C=128) in R2; d2 scratch = R3 ----
    sq_kernel<64><<<BN / 256, 256, 0, stream>>>(R1, sqb);
    gram_kernel<64><<<GRAM_GRID, 256, 0, stream>>>(R1, sqb, R3);
    topk_kernel<<<TOPK_GRID, 256, 0, stream>>>(R3, idx);
    point_mlp_kernel<64, 128><<<BN, 128, 0, stream>>>(R1, W2, b2, g2, be2, R2, R3);
    combine_kernel<128><<<BN, 128, 0, stream>>>(R2, R3, idx, R2); // h2 = R2

    // ---- Layer 3: h2 (D=128) -> h3 (C=256) in R3; d2 scratch = R1 ----
    sq_kernel<128><<<BN / 256, 256, 0, stream>>>(R2, sqb);
    gram_kernel<128><<<GRAM_GRID, 256, 0, stream>>>(R2, sqb, R1);
    topk_kernel<<<TOPK_GRID, 256, 0, stream>>>(R1, idx);
    point_mlp_kernel<128, 256><<<BN, 256, 0, stream>>>(R2, W3, b3, g3, be3, R3, R1);
    combine_kernel<256><<<BN, 256, 0, stream>>>(R3, R1, idx, R3); // h3 = R3

    // ---- Head ----
    head_kernel<<<NBATCH, 256, 0, stream>>>(R3, Wf1, bf1, gf, bef, Wf2, bf2, out);
}

// Round 4
// 486.483 us; speedup vs baseline: 3.3808x; 1.5740x over previous
//
#include <hip/hip_runtime.h>
#include <cstdint>
#include <cstddef>

#define KNN 16
#define NPTS 256
#define NBATCH 128

static constexpr float BN_SCALE_F = 0.9999950000374997f; // 1/sqrt(1+1e-5)

__device__ inline unsigned int f32_ord(float f) {
    unsigned int u = __float_as_uint(f);
    return (u & 0x80000000u) ? ~u : (u | 0x80000000u);
}

// ---------------------------------------------------------------------------
// sq[t] = sum_d x[t][d]^2, sequential fmaf chain (matches reference assoc).
// ---------------------------------------------------------------------------
template<int D>
__global__ __launch_bounds__(256) void sq_kernel(const float* __restrict__ x,
                                                 float* __restrict__ sq) {
    const int t = blockIdx.x * 256 + threadIdx.x;
    const float* r = x + (size_t)t * D;
    float s = 0.f;
    #pragma unroll
    for (int d = 0; d < D; ++d) s = fmaf(r[d], r[d], s);
    sq[t] = s;
}

// ---------------------------------------------------------------------------
// Distance GEMM: d2[b][i][j] = (sq_i + sq_j) - 2*dot(x_i, x_j), diag = +INF.
// (unchanged from r3 — bit-exact vs reference top_k for 2 rounds)
// ---------------------------------------------------------------------------
template<int D>
__global__ __launch_bounds__(256) void gram_kernel(const float* __restrict__ x,
                                                   const float* __restrict__ sq,
                                                   float* __restrict__ d2) {
    constexpr int KS = (D >= 16) ? 16 : D;
    const int t  = threadIdx.x;
    const int tx = t & 15, ty = t >> 4;
    const int b    = blockIdx.x >> 4;
    const int tile = blockIdx.x & 15;
    const int i0 = (tile & 3) * 64;
    const int j0 = (tile >> 2) * 64;
    const int base = b * NPTS;

    __shared__ float As[KS][68];
    __shared__ float Bs[KS][68];

    float acc[4][4] = {};
    for (int k0 = 0; k0 < D; k0 += KS) {
        if constexpr (D % 16 == 0) {
            const int r  = t >> 2;
            const int cq = (t & 3) * 4;
            const float4 va = *(const float4*)(x + (size_t)(base + i0 + r) * D + k0 + cq);
            const float4 vb = *(const float4*)(x + (size_t)(base + j0 + r) * D + k0 + cq);
            As[cq + 0][r] = va.x; As[cq + 1][r] = va.y;
            As[cq + 2][r] = va.z; As[cq + 3][r] = va.w;
            Bs[cq + 0][r] = vb.x; Bs[cq + 1][r] = vb.y;
            Bs[cq + 2][r] = vb.z; Bs[cq + 3][r] = vb.w;
        } else {
            for (int e = t; e < 64 * KS; e += 256) {
                const int r = e / KS, c = e % KS;
                As[c][r] = x[(size_t)(base + i0 + r) * D + k0 + c];
                Bs[c][r] = x[(size_t)(base + j0 + r) * D + k0 + c];
            }
        }
        __syncthreads();
        #pragma unroll
        for (int kk = 0; kk < KS; ++kk) {
            const float4 av = *(const float4*)&As[kk][ty * 4];
            const float4 bv = *(const float4*)&Bs[kk][tx * 4];
            const float am[4] = {av.x, av.y, av.z, av.w};
            const float bm[4] = {bv.x, bv.y, bv.z, bv.w};
            #pragma unroll
            for (int m = 0; m < 4; ++m)
                #pragma unroll
                for (int n = 0; n < 4; ++n)
                    acc[m][n] = fmaf(am[m], bm[n], acc[m][n]);
        }
        __syncthreads();
    }

    float sqi[4], sqj[4];
    #pragma unroll
    for (int m = 0; m < 4; ++m) {
        sqi[m] = sq[base + i0 + ty * 4 + m];
        sqj[m] = sq[base + j0 + tx * 4 + m];
    }
    #pragma unroll
    for (int m = 0; m < 4; ++m) {
        const int gi = i0 + ty * 4 + m;
        float v[4];
        #pragma unroll
        for (int n = 0; n < 4; ++n) {
            v[n] = (sqi[m] + sqj[n]) - 2.f * acc[m][n];
            if (gi == j0 + tx * 4 + n) v[n] = INFINITY;
        }
        float4* dst = (float4*)(d2 + ((size_t)b << 16) + (size_t)gi * NPTS + j0 + tx * 4);
        *dst = make_float4(v[0], v[1], v[2], v[3]);
    }
}

// ---------------------------------------------------------------------------
// Top-16 selection, pure VALU (unchanged from r3).
// ---------------------------------------------------------------------------
__global__ __launch_bounds__(256) void topk_kernel(const float* __restrict__ d2,
                                                   int* __restrict__ idx) {
    const int t = threadIdx.x;
    const int p = t >> 3;
    const int q = t & 7;
    const int ig = blockIdx.x * 32 + p;
    const float* row = d2 + (size_t)ig * NPTS;

    unsigned long long L[16];
    #pragma unroll
    for (int r = 0; r < 16; ++r) L[r] = ~0ull;

    const int jb = q * 32;
    #pragma unroll
    for (int jj = 0; jj < 32; jj += 4) {
        const float4 v4 = *(const float4*)(row + jb + jj);
        const float vv[4] = {v4.x, v4.y, v4.z, v4.w};
        #pragma unroll
        for (int e = 0; e < 4; ++e) {
            const unsigned long long key =
                ((unsigned long long)f32_ord(vv[e]) << 32) |
                (unsigned int)(jb + jj + e);
            #pragma unroll
            for (int r = 15; r >= 1; --r)
                L[r] = (key < L[r]) ? ((key < L[r - 1]) ? L[r - 1] : key) : L[r];
            L[0] = (key < L[0]) ? key : L[0];
        }
    }

    __shared__ unsigned long long K[256][17];
    #pragma unroll
    for (int r = 0; r < 16; ++r) K[t][r] = L[r];
    __syncthreads();

    if (t < 32) {
        const int pp  = t;
        const int igo = blockIdx.x * 32 + pp;
        int h[8];
        unsigned long long v[8];
        #pragma unroll
        for (int c = 0; c < 8; ++c) { h[c] = 0; v[c] = K[pp * 8 + c][0]; }
        int outj[16];
        #pragma unroll
        for (int r = 0; r < 16; ++r) {
            unsigned long long best = v[0];
            #pragma unroll
            for (int c = 1; c < 8; ++c) best = (v[c] < best) ? v[c] : best;
            outj[r] = (int)(unsigned int)(best & 0xffffffffull);
            #pragma unroll
            for (int c = 0; c < 8; ++c) {
                const bool hit = (v[c] == best);
                const int hn = h[c] + (hit ? 1 : 0);
                const unsigned long long nv = K[pp * 8 + c][hn & 15];
                v[c] = hit ? ((hn < 16) ? nv : ~0ull) : v[c];
                h[c] = hn;
            }
        }
        int4* op = (int4*)(idx + (size_t)igo * KNN);
        op[0] = make_int4(outj[0],  outj[1],  outj[2],  outj[3]);
        op[1] = make_int4(outj[4],  outj[5],  outj[6],  outj[7]);
        op[2] = make_int4(outj[8],  outj[9],  outj[10], outj[11]);
        op[3] = make_int4(outj[12], outj[13], outj[14], outj[15]);
    }
}

// ---------------------------------------------------------------------------
// Factorized edge-MLP as a tiled GEMM: X (M x D) @ W' (D x 2C) where
//   W'[:, 0:C ) = Wt - Wb  (difference taken during LDS staging -> the
//                           per-output fmaf chain over ascending d is
//                           BIT-IDENTICAL to rounds 1-3's point_mlp)
//   W'[:, C:2C) = Wb
// Epilogue: A = gc*U ; Bv = gc*(V + b) + be  (gc = g*BN_SCALE).
// Block tile 128x128 (BM x BN_), thread tile 8x8, KT=min(D,16).
// ---------------------------------------------------------------------------
template<int D, int C, int BNW>
__global__ __launch_bounds__(256) void mlp_gemm_kernel(
        const float* __restrict__ x, const float* __restrict__ W,
        const float* __restrict__ bias, const float* __restrict__ g,
        const float* __restrict__ be,
        float* __restrict__ A, float* __restrict__ Bv) {
    constexpr int BM = 128;
    constexpr int KT = (D >= 16) ? 16 : D;
    const int t  = threadIdx.x;
    const int m0 = blockIdx.x * BM;
    const int n0 = blockIdx.y * BNW;
    const int tx = t & 15;   // col group (8 cols)
    const int ty = t >> 4;   // row group (8 rows)

    __shared__ float Xs[KT][BM + 4];
    __shared__ float Ws[KT][BNW + 4];

    float acc[8][8] = {};

    for (int k0 = 0; k0 < D; k0 += KT) {
        // ---- stage X tile (BM x KT), transposed to [k][m] ----
        if constexpr (D % 16 == 0) {
            const int r  = t >> 1;          // 0..127
            const int cq = (t & 1) * 8;     // 0 or 8
            const float* src = x + (size_t)(m0 + r) * D + k0 + cq;
            const float4 v0 = *(const float4*)(src);
            const float4 v1 = *(const float4*)(src + 4);
            Xs[cq + 0][r] = v0.x; Xs[cq + 1][r] = v0.y;
            Xs[cq + 2][r] = v0.z; Xs[cq + 3][r] = v0.w;
            Xs[cq + 4][r] = v1.x; Xs[cq + 5][r] = v1.y;
            Xs[cq + 6][r] = v1.z; Xs[cq + 7][r] = v1.w;
        } else {
            for (int e = t; e < BM * KT; e += 256) {
                const int r = e / KT, c = e % KT;
                Xs[c][r] = x[(size_t)(m0 + r) * D + k0 + c];
            }
        }
        // ---- stage W' tile (KT x BNW) ----
        if constexpr (D % 16 == 0) {
            const int wk = t >> 4;           // 0..15 (k row)
            const int nq = (t & 15) * 8;     // col offset
            const int gn = n0 + nq;
            const int kr = k0 + wk;
            if (gn < C) {
                const float* pt = W + (size_t)kr * C + gn;
                const float* pb = W + (size_t)(D + kr) * C + gn;
                const float4 t0 = *(const float4*)(pt);
                const float4 t1 = *(const float4*)(pt + 4);
                const float4 b0 = *(const float4*)(pb);
                const float4 b1 = *(const float4*)(pb + 4);
                Ws[wk][nq + 0] = t0.x - b0.x; Ws[wk][nq + 1] = t0.y - b0.y;
                Ws[wk][nq + 2] = t0.z - b0.z; Ws[wk][nq + 3] = t0.w - b0.w;
                Ws[wk][nq + 4] = t1.x - b1.x; Ws[wk][nq + 5] = t1.y - b1.y;
                Ws[wk][nq + 6] = t1.z - b1.z; Ws[wk][nq + 7] = t1.w - b1.w;
            } else {
                const float* pb = W + (size_t)(D + kr) * C + (gn - C);
                const float4 b0 = *(const float4*)(pb);
                const float4 b1 = *(const float4*)(pb + 4);
                Ws[wk][nq + 0] = b0.x; Ws[wk][nq + 1] = b0.y;
                Ws[wk][nq + 2] = b0.z; Ws[wk][nq + 3] = b0.w;
                Ws[wk][nq + 4] = b1.x; Ws[wk][nq + 5] = b1.y;
                Ws[wk][nq + 6] = b1.z; Ws[wk][nq + 7] = b1.w;
            }
        } else {
            for (int e = t; e < KT * BNW; e += 256) {
                const int k = e >> 7, n = e & (BNW - 1);
                const int gn = n0 + n, kr = k0 + k;
                if (gn < C)
                    Ws[k][n] = W[(size_t)kr * C + gn] - W[(size_t)(D + kr) * C + gn];
                else
                    Ws[k][n] = W[(size_t)(D + kr) * C + (gn - C)];
            }
        }
        __syncthreads();

        #pragma unroll
        for (int kk = 0; kk < KT; ++kk) {
            float xm[8], wn[8];
            *(float4*)&xm[0] = *(const float4*)&Xs[kk][ty * 8];
            *(float4*)&xm[4] = *(const float4*)&Xs[kk][ty * 8 + 4];
            *(float4*)&wn[0] = *(const float4*)&Ws[kk][tx * 8];
            *(float4*)&wn[4] = *(const float4*)&Ws[kk][tx * 8 + 4];
            #pragma unroll
            for (int m = 0; m < 8; ++m)
                #pragma unroll
                for (int n = 0; n < 8; ++n)
                    acc[m][n] = fmaf(xm[m], wn[n], acc[m][n]);
        }
        __syncthreads();
    }

    // ---- epilogue: affine + route halves (8-col quads never straddle C) ----
    const int gn = n0 + tx * 8;
    if (gn < C) {
        float fac[8];
        #pragma unroll
        for (int e = 0; e < 8; ++e) fac[e] = g[gn + e] * BN_SCALE_F;
        #pragma unroll
        for (int m = 0; m < 8; ++m) {
            float o[8];
            #pragma unroll
            for (int e = 0; e < 8; ++e) o[e] = fac[e] * acc[m][e];
            float* dst = A + (size_t)(m0 + ty * 8 + m) * C + gn;
            *(float4*)(dst)     = make_float4(o[0], o[1], o[2], o[3]);
            *(float4*)(dst + 4) = make_float4(o[4], o[5], o[6], o[7]);
        }
    } else {
        const int cb = gn - C;
        float fac[8], bb[8], bee[8];
        #pragma unroll
        for (int e = 0; e < 8; ++e) {
            fac[e] = g[cb + e] * BN_SCALE_F;
            bb[e]  = bias[cb + e];
            bee[e] = be[cb + e];
        }
        #pragma unroll
        for (int m = 0; m < 8; ++m) {
            float o[8];
            #pragma unroll
            for (int e = 0; e < 8; ++e)
                o[e] = fmaf(fac[e], acc[m][e] + bb[e], bee[e]);
            float* dst = Bv + (size_t)(m0 + ty * 8 + m) * C + cb;
            *(float4*)(dst)     = make_float4(o[0], o[1], o[2], o[3]);
            *(float4*)(dst + 4) = make_float4(o[4], o[5], o[6], o[7]);
        }
    }
}

// ---------------------------------------------------------------------------
// Combine: out[i][c] = relu(A[i][c] + max_{j in knn(i)} Bv[j][c]). out aliases A.
// ---------------------------------------------------------------------------
template<int C>
__global__ __launch_bounds__(C) void combine_kernel(
        const float* A, const float* __restrict__ Bv,
        const int* __restrict__ idx, float* out) {
    const int bi = blockIdx.x;
    const int c  = threadIdx.x;
    __shared__ int nbr[KNN];
    if (c < KNN) nbr[c] = idx[(size_t)bi * KNN + c];
    __syncthreads();
    const int b0 = bi & ~255;
    float mx = -INFINITY;
    #pragma unroll
    for (int kk = 0; kk < KNN; ++kk)
        mx = fmaxf(mx, Bv[(size_t)(b0 + nbr[kk]) * C + c]);
    float a = A[(size_t)bi * C + c];
    out[(size_t)bi * C + c] = fmaxf(a + mx, 0.f);
}

// ---------------------------------------------------------------------------
// Head: global max-pool over N, then 2 tiny FCs. One block per batch.
// ---------------------------------------------------------------------------
__global__ __launch_bounds__(256) void head_kernel(
        const float* __restrict__ h3, const float* __restrict__ Wf1,
        const float* __restrict__ bf1, const float* __restrict__ gf,
        const float* __restrict__ bef, const float* __restrict__ Wf2,
        const float* __restrict__ bf2, float* __restrict__ out) {
    const int b   = blockIdx.x;
    const int tid = threadIdx.x;
    __shared__ float p[256];
    __shared__ float f[128];
    const float* hb = h3 + (size_t)b * NPTS * 256;
    float mx = -INFINITY;
    for (int n = 0; n < NPTS; ++n) mx = fmaxf(mx, hb[(size_t)n * 256 + tid]);
    p[tid] = mx;
    __syncthreads();
    if (tid < 128) {
        float acc = bf1[tid];
        for (int d = 0; d < 256; ++d)
            acc = fmaf(p[d], Wf1[(size_t)d * 128 + tid], acc);
        float v = gf[tid] * (acc * BN_SCALE_F) + bef[tid];
        f[tid] = fmaxf(v, 0.f);
    }
    __syncthreads();
    if (tid < 12) {
        float acc = bf2[tid];
        for (int d = 0; d < 128; ++d)
            acc = fmaf(f[d], Wf2[(size_t)d * 12 + tid], acc);
        out[(size_t)b * 12 + tid] = acc;
    }
}

extern "C" void kernel_launch(void* const* d_in, const int* in_sizes, int n_in,
                              void* d_out, int out_size, void* d_ws, size_t ws_size,
                              hipStream_t stream) {
    const float* x   = (const float*)d_in[0];
    const float* W1  = (const float*)d_in[1];
    const float* b1  = (const float*)d_in[2];
    const float* g1  = (const float*)d_in[3];
    const float* be1 = (const float*)d_in[4];
    const float* W2  = (const float*)d_in[5];
    const float* b2  = (const float*)d_in[6];
    const float* g2  = (const float*)d_in[7];
    const float* be2 = (const float*)d_in[8];
    const float* W3  = (const float*)d_in[9];
    const float* b3  = (const float*)d_in[10];
    const float* g3  = (const float*)d_in[11];
    const float* be3 = (const float*)d_in[12];
    const float* Wf1 = (const float*)d_in[13];
    const float* bf1 = (const float*)d_in[14];
    const float* gf  = (const float*)d_in[15];
    const float* bef = (const float*)d_in[16];
    const float* Wf2 = (const float*)d_in[17];
    const float* bf2 = (const float*)d_in[18];
    float* out = (float*)d_out;

    char* ws = (char*)d_ws;
    const size_t idx_bytes = (size_t)NBATCH * NPTS * KNN * sizeof(int);   // 2 MB
    const size_t reg_bytes = (size_t)NBATCH * NPTS * 256 * sizeof(float); // 32 MB
    int*   idx = (int*)ws;
    float* R1  = (float*)(ws + idx_bytes);
    float* R2  = (float*)(ws + idx_bytes + reg_bytes);
    float* R3  = (float*)(ws + idx_bytes + 2 * reg_bytes);
    float* sqb = (float*)(ws + idx_bytes + 3 * reg_bytes);                // 128 KB

    const int BN = NBATCH * NPTS;        // 32768 points
    const int GRAM_GRID = NBATCH * 16;   // 2048 blocks
    const int TOPK_GRID = BN / 32;       // 1024 blocks
    const int MB = BN / 128;             // 256 m-blocks for the MLP GEMM

    // ---- Layer 1: x (D=6) -> h1 (C=64) in R1; d2 scratch = R3 ----
    sq_kernel<6><<<BN / 256, 256, 0, stream>>>(x, sqb);
    gram_kernel<6><<<GRAM_GRID, 256, 0, stream>>>(x, sqb, R3);
    topk_kernel<<<TOPK_GRID, 256, 0, stream>>>(R3, idx);
    mlp_gemm_kernel<6, 64, 128><<<dim3(MB, 1), 256, 0, stream>>>(
        x, W1, b1, g1, be1, R1, R2);
    combine_kernel<64><<<BN, 64, 0, stream>>>(R1, R2, idx, R1);   // h1 = R1

    // ---- Layer 2: h1 (D=64) -> h2 (C=128) in R2; d2 scratch = R3 ----
    sq_kernel<64><<<BN / 256, 256, 0, stream>>>(R1, sqb);
    gram_kernel<64><<<GRAM_GRID, 256, 0, stream>>>(R1, sqb, R3);
    topk_kernel<<<TOPK_GRID, 256, 0, stream>>>(R3, idx);
    mlp_gemm_kernel<64, 128, 128><<<dim3(MB, 2), 256, 0, stream>>>(
        R1, W2, b2, g2, be2, R2, R3);
    combine_kernel<128><<<BN, 128, 0, stream>>>(R2, R3, idx, R2); // h2 = R2

    // ---- Layer 3: h2 (D=128) -> h3 (C=256) in R3; d2 scratch = R1 ----
    sq_kernel<128><<<BN / 256, 256, 0, stream>>>(R2, sqb);
    gram_kernel<128><<<GRAM_GRID, 256, 0, stream>>>(R2, sqb, R1);
    topk_kernel<<<TOPK_GRID, 256, 0, stream>>>(R1, idx);
    mlp_gemm_kernel<128, 256, 128><<<dim3(MB, 4), 256, 0, stream>>>(
        R2, W3, b3, g3, be3, R3, R1);
    combine_kernel<256><<<BN, 256, 0, stream>>>(R3, R1, idx, R3); // h3 = R3

    // ---- Head ----
    head_kernel<<<NBATCH, 256, 0, stream>>>(R3, Wf1, bf1, gf, bef, Wf2, bf2, out);
}